// Round 16
// baseline (227.572 us; speedup 1.0000x reference)
//
#include <hip/hip_runtime.h>
#include <cstdint>

// ---------------------------------------------------------------------------
// GCN graph classification on MI355X (gfx950), v16.
//   v15 with BSLICE 64->32: halves slice-partial + cursor traffic and the
//   k_norms per-node reduction loop; per-slice counts still < 2^16.
//   k_setup: packed hist(src/dst) + castT + prep + counter zero
//   k_norms: partial sums -> cj,ci,indeg; slice prefix -> CSR cursors
//   k_fillcast: CSR fill (LDS cursors) ++ xb = bf16(cj*x)
//   a1[n] = sum_{e: dst=n} xb[src]                (unroll-8, predicated tail)
//   k_gw:  h1t8 = bf16(cj*relu((a1@W1)*ci+b1))  ||  Wg[g][s] build
//   tpart = Wg @ h1 (MFMA) ; tred ; final
// ---------------------------------------------------------------------------

typedef __attribute__((ext_vector_type(8))) short short8v;
typedef __attribute__((ext_vector_type(4))) float f32x4;

constexpr int RSPLIT = 4;    // node ranges for fill/wgn (50KB int/f32 LDS)
constexpr int HSPLIT = 2;    // node ranges for packed hist (50KB u32 LDS)
constexpr int BSLICE = 32;   // edge slices (E/32 = 25K < 2^16, ushort-safe)
constexpr int LDSN = 12544;  // >= ceil(50048/4) ints/floats
constexpr int LDSH = 12544;  // packed u32 counters (covers 25088 nodes)

static __device__ __forceinline__ unsigned f2bf(float f) {
  unsigned u = __float_as_uint(f);
  u += 0x7FFFu + ((u >> 16) & 1u);   // RTNE
  return u >> 16;
}
static __device__ __forceinline__ float bf2f(unsigned h) {
  return __uint_as_float(h << 16);
}

// Fused setup: blocks [0,128) hist (h in {src,dst} x 32 slices x 2 ranges,
// packed dual-ushort counters in u32 LDS); [128,256) castT(W1->BT1);
// [256,513) prep. Block 0 thread 0 zeroes the scan counter.
__global__ __launch_bounds__(256)
void k_setup(const int* __restrict__ src, const int* __restrict__ dst,
             const float* __restrict__ W1, const float* __restrict__ W2,
             const float* __restrict__ Wl, const float* __restrict__ b2,
             const float* __restrict__ bl,
             unsigned short* __restrict__ outpart, unsigned short* __restrict__ inpart,
             unsigned short* __restrict__ BT1, float* __restrict__ Wc,
             float* __restrict__ cb, int* __restrict__ counter,
             int E, int N, int L) {
  __shared__ unsigned cnt_s[LDSH];
  __shared__ float w2row[256];
  const int blk = blockIdx.x;
  const int tid = threadIdx.x;
  if (blk == 0 && tid == 0) *counter = 0;

  const int NHIST = 2 * BSLICE * HSPLIT;      // 128
  if (blk < NHIST) {                          // packed histogram
    const int h = blk >> 6;                   // 0: src, 1: dst
    const int sub = blk & 63;
    const int b = sub >> 1, r = sub & 1;
    const int* idx = h ? dst : src;
    unsigned short* part = h ? inpart : outpart;
    const int RN = (N + HSPLIT - 1) / HSPLIT; // 25000 (even)
    const int r0 = r * RN;
    int rlen = N - r0; if (rlen > RN) rlen = RN; if (rlen < 0) rlen = 0;
    const int words = (rlen + 1) >> 1;
    for (int i = tid; i < words; i += 256) cnt_s[i] = 0;
    __syncthreads();
    const int e0 = (int)((long long)E * b / BSLICE);
    const int e1 = (int)((long long)E * (b + 1) / BSLICE);
    for (int e = e0 + tid; e < e1; e += 256) {
      int v = idx[e] - r0;
      if (v >= 0 && v < rlen)
        atomicAdd(&cnt_s[v >> 1], 1u << ((v & 1) * 16));
    }
    __syncthreads();
    // part + b*N + r0 is 4B-aligned (N, r0 even); u32 = two ushort counts.
    unsigned* dp = (unsigned*)(part + (size_t)b * N + r0);
    for (int i = tid; i < words; i += 256) dp[i] = cnt_s[i];
  } else if (blk < NHIST + 128) {             // castT: W1[128][256] -> BT1
    int i = (blk - NHIST) * 256 + tid;        // 32768 elems
    int k = i >> 8, nn = i & 255;
    BT1[(size_t)nn * 128 + k] = (unsigned short)f2bf(W1[i]);
  } else {                                    // prep
    int c = blk - (NHIST + 128);              // 0..256
    if (c < 256) {
      w2row[tid] = W2[(size_t)c * 256 + tid]; // coalesced stage
      __syncthreads();
      int l = tid;
      if (l < L) {
        float a = 0.f;
#pragma unroll 8
        for (int m = 0; m < 256; ++m) a += w2row[m] * Wl[(size_t)m * L + l];
        Wc[(size_t)c * L + l] = a;
      }
    } else {
      int l = tid;
      if (l < L) {
        float a = bl[l];
#pragma unroll 8
        for (int m = 0; m < 256; ++m) a += b2[m] * Wl[(size_t)m * L + l];
        cb[l] = a;
      }
    }
  }
}

// Sum partials -> cj/ci/indeg_tot; wave-scan + bump -> row_start; prefix over
// slices -> cursor_base[b][n] (exact CSR write cursors for fill).
__global__ void k_norms(const unsigned short* __restrict__ outpart,
                        const unsigned short* __restrict__ inpart,
                        float* __restrict__ cj, float* __restrict__ ci,
                        int* __restrict__ indeg_tot, int* __restrict__ row_start,
                        int* __restrict__ cursor_base, int* __restrict__ counter, int N) {
  int i = blockIdx.x * blockDim.x + threadIdx.x;
  int din = 0, dout = 0;
  if (i < N) {
    for (int b = 0; b < BSLICE; ++b) {
      din += inpart[(size_t)b * N + i];
      dout += outpart[(size_t)b * N + i];
    }
    cj[i] = rsqrtf((float)(dout > 1 ? dout : 1));
    ci[i] = rsqrtf((float)(din  > 1 ? din  : 1));
    indeg_tot[i] = din;
  }
  int lane = threadIdx.x & 63;
  int inc = din;
#pragma unroll
  for (int off = 1; off < 64; off <<= 1) {
    int o = __shfl_up(inc, off);
    if (lane >= off) inc += o;
  }
  int excl = inc - din;
  int wsum = __shfl(inc, 63);
  int base = 0;
  if (lane == 0) base = atomicAdd(counter, wsum);
  base = __shfl(base, 0);
  if (i < N) {
    int rs = base + excl;
    row_start[i] = rs;
    for (int b = 0; b < BSLICE; ++b) {
      cursor_base[(size_t)b * N + i] = rs;
      rs += inpart[(size_t)b * N + i];
    }
  }
}

// Fused: blocks [0,128) CSR fill (slice b, range r); rest = bf16(cj*x) cast.
__global__ __launch_bounds__(256)
void k_fillcast(const int* __restrict__ src, const int* __restrict__ dst,
                const int* __restrict__ cursor_base, int* __restrict__ csr_src,
                const float4* __restrict__ x, const float* __restrict__ cj,
                unsigned short* __restrict__ xb, int E, int N) {
  __shared__ int cur_s[LDSN];
  const int blk = blockIdx.x;
  if (blk < RSPLIT * BSLICE) {
    const int b = blk >> 2, r = blk & 3;
    const int RN = (N + RSPLIT - 1) / RSPLIT;
    const int r0 = r * RN;
    int rlen = N - r0; if (rlen > RN) rlen = RN; if (rlen < 0) rlen = 0;
    const int* cb_ = cursor_base + (size_t)b * N + r0;
    for (int i = threadIdx.x; i < rlen; i += 256) cur_s[i] = cb_[i];
    __syncthreads();
    const int e0 = (int)((long long)E * b / BSLICE);
    const int e1 = (int)((long long)E * (b + 1) / BSLICE);
    for (int e = e0 + (int)threadIdx.x; e < e1; e += 256) {
      int d = dst[e] - r0;
      if (d >= 0 && d < rlen) {
        int pos = atomicAdd(&cur_s[d], 1);
        csr_src[pos] = src[e];
      }
    }
  } else {
    int i = (blk - RSPLIT * BSLICE) * 256 + (int)threadIdx.x;
    if (i < N * 32) {
      float c = cj[i >> 5];            // 32 float4 per 128-wide row
      float4 v = x[i];
      uint2 r;
      r.x = f2bf(c * v.x) | (f2bf(c * v.y) << 16);
      r.y = f2bf(c * v.z) | (f2bf(c * v.w) << 16);
      *(uint2*)(xb + (size_t)i * 4) = r;
    }
  }
}

// Row-sum gather: wave per node, lane owns 1 uint (2 cols); unroll-8 with
// clamped+masked final batch (no serial tail).
__global__ __launch_bounds__(256)
void k_spmm(const unsigned* __restrict__ feat,
            const int* __restrict__ row_start, const int* __restrict__ cnts,
            const int* __restrict__ csr_src, unsigned* __restrict__ out, int N) {
  const int n = blockIdx.x * 4 + (threadIdx.x >> 6);
  if (n >= N) return;
  const int t = threadIdx.x & 63;
  const int beg = __builtin_amdgcn_readfirstlane(row_start[n]);
  const int cnt = __builtin_amdgcn_readfirstlane(cnts[n]);
  float acc0 = 0.f, acc1 = 0.f;

  for (int k = 0; k < cnt; k += 8) {
    int s[8];
#pragma unroll
    for (int u = 0; u < 8; ++u) {
      int kk = k + u;
      s[u] = csr_src[beg + (kk < cnt ? kk : cnt - 1)];
    }
    unsigned w[8];
#pragma unroll
    for (int u = 0; u < 8; ++u) w[u] = feat[(size_t)s[u] * 64 + t];
#pragma unroll
    for (int u = 0; u < 8; ++u) {
      if (k + u >= cnt) w[u] = 0;      // masked: bf16 +0.0
      acc0 += bf2f(w[u] & 0xFFFF);
      acc1 += bf2f(w[u] >> 16);
    }
  }
  out[(size_t)n * 64 + t] = f2bf(acc0) | (f2bf(acc1) << 16);
}

// Fused GEMM1 || Wg-build. Blocks [0,RB): h1t8 = f(a1@W1) (MFMA, 64KB LDS);
// blocks [RB, RB+RSPLIT*G): Wg row slices (50KB of the same LDS).
__global__ __launch_bounds__(256, 2)
void k_gw(const unsigned short* __restrict__ A, const unsigned short* __restrict__ BT,
          const float* __restrict__ ci, const float* __restrict__ bias,
          const float* __restrict__ cjv, unsigned short* __restrict__ out, int M,
          const int* __restrict__ gids, const int* __restrict__ row_start,
          const int* __restrict__ cnts, const int* __restrict__ csr_src,
          float* __restrict__ Wg, int Npad, int G, int RB) {
  __shared__ unsigned short Bs[64 * 64 * 8];   // 64KB (gemm); reused by wgn
  const int tid = threadIdx.x;

  if ((int)blockIdx.x < RB) {
    // ---------------- GEMM1 ----------------
    constexpr int K = 128;
    const int lane = tid & 63;
    const int wave = tid >> 6;
    const int l15 = lane & 15;
    const int kA = (lane >> 4) * 8;

#pragma unroll
    for (int it = 0; it < 16; ++it) {
      int c = it * 256 + tid;
      int f = c >> 6, l = c & 63;
      int ct = f & 15, kb = f >> 4;
      int col = ct * 16 + (l & 15);
      int ko = kb * 32 + (l >> 4) * 8;
      *(uint4*)&Bs[(size_t)c * 8] = *(const uint4*)(BT + (size_t)col * K + ko);
    }
    __syncthreads();

    const int rowW = blockIdx.x * 128 + wave * 32;
    const unsigned short* aP0 = A + (size_t)(rowW + l15) * K + kA;
    const unsigned short* aP1 = aP0 + (size_t)16 * K;

    short8v a0[4], a1v[4];
#pragma unroll
    for (int kb = 0; kb < 4; ++kb) {
      a0[kb] = *(const short8v*)(aP0 + kb * 32);
      a1v[kb] = *(const short8v*)(aP1 + kb * 32);
    }

    f32x4 acc0[16], acc1[16];
#pragma unroll
    for (int i = 0; i < 16; ++i) {
      acc0[i] = (f32x4){0.f, 0.f, 0.f, 0.f};
      acc1[i] = (f32x4){0.f, 0.f, 0.f, 0.f};
    }

    const unsigned short* bL = Bs + lane * 8;
#pragma unroll
    for (int kb = 0; kb < 4; ++kb) {
#pragma unroll
      for (int ct = 0; ct < 16; ++ct) {
        short8v bv = *(const short8v*)(bL + (size_t)(kb * 16 + ct) * 512);
        acc0[ct] = __builtin_amdgcn_mfma_f32_16x16x32_bf16(a0[kb], bv, acc0[ct], 0, 0, 0);
        acc1[ct] = __builtin_amdgcn_mfma_f32_16x16x32_bf16(a1v[kb], bv, acc1[ct], 0, 0, 0);
      }
    }

#pragma unroll
    for (int half = 0; half < 2; ++half) {
      const f32x4* acc = half ? acc1 : acc0;
      const int row0 = rowW + (lane >> 4) * 4 + half * 16;   // multiple of 4
      float cir[4], cjr[4];
#pragma unroll
      for (int r = 0; r < 4; ++r) {
        int rI = row0 + r; if (rI > M - 1) rI = M - 1;
        cir[r] = ci[rI];
        cjr[r] = cjv[rI];
      }
      unsigned short* ob = out + (size_t)(row0 >> 3) * 2048 + (row0 & 7);
#pragma unroll
      for (int ct = 0; ct < 16; ++ct) {
        int col = ct * 16 + l15;
        float bb = bias[col];
        unsigned h0 = f2bf(fmaxf(acc[ct][0] * cir[0] + bb, 0.f) * cjr[0]);
        unsigned h1 = f2bf(fmaxf(acc[ct][1] * cir[1] + bb, 0.f) * cjr[1]);
        unsigned h2 = f2bf(fmaxf(acc[ct][2] * cir[2] + bb, 0.f) * cjr[2]);
        unsigned h3 = f2bf(fmaxf(acc[ct][3] * cir[3] + bb, 0.f) * cjr[3]);
        uint2 pk;
        pk.x = h0 | (h1 << 16);
        pk.y = h2 | (h3 << 16);
        *(uint2*)(ob + (size_t)col * 8) = pk;
      }
    }
  } else {
    // ---------------- Wg build (LDS-owned row slices) ----------------
    float* row_s = (float*)Bs;                 // 50KB of the 64KB
    const int bid = (int)blockIdx.x - RB;
    const int g = bid % G;
    const int r = bid / G;
    const int RNW = (Npad + RSPLIT - 1) / RSPLIT;
    const int r0 = r * RNW;
    int rlen = Npad - r0; if (rlen > RNW) rlen = RNW; if (rlen < 0) rlen = 0;
    for (int i = tid; i < rlen; i += 256) row_s[i] = 0.f;
    __syncthreads();
    int N_ = M;                                // node count
    int lo = 0, hi = N_;
    while (lo < hi) { int m = (lo + hi) >> 1; if (gids[m] < g) lo = m + 1; else hi = m; }
    int lo2 = lo, hi2 = N_;
    while (lo2 < hi2) { int m = (lo2 + hi2) >> 1; if (gids[m] < g + 1) lo2 = m + 1; else hi2 = m; }
    for (int n = lo + tid; n < lo2; n += 256) {
      float cin = ci[n];
      int beg = row_start[n];
      int cnt = cnts[n];
      for (int k = 0; k < cnt; ++k) {
        int s = csr_src[beg + k] - r0;
        if (s >= 0 && s < rlen) atomicAdd(&row_s[s], cin);
      }
    }
    __syncthreads();
    float* wr = Wg + (size_t)g * Npad + r0;
    for (int i = tid; i < rlen; i += 256) wr[i] = row_s[i];
  }
}

// tpart[blk] = bf16(Wg[:, kchunk]) @ h1[kchunk, :]; K-chunk 256 per block.
__global__ __launch_bounds__(256)
void k_tgemm(const float* __restrict__ Wg, const unsigned short* __restrict__ h1t8,
             float* __restrict__ tpart, int Npad) {
  __shared__ unsigned short As[64][136];
  const int tid = threadIdx.x;
  const int lane = tid & 63;
  const int wv = tid >> 6;
  const int l15 = lane & 15;
  const int kA = (lane >> 4) * 8;

  f32x4 acc[16];
#pragma unroll
  for (int i = 0; i < 16; ++i) acc[i] = (f32x4){0.f, 0.f, 0.f, 0.f};

  const int kbeg = blockIdx.x * 256;
#pragma unroll
  for (int step = 0; step < 2; ++step) {
    int k0 = kbeg + step * 128;
    if (k0 >= Npad) break;
#pragma unroll
    for (int it = 0; it < 8; ++it) {
      int idx = it * 256 + tid;
      int r = idx >> 5, q = idx & 31;
      float4 v = *(const float4*)(Wg + (size_t)r * Npad + k0 + q * 4);
      uint2 pk;
      pk.x = f2bf(v.x) | (f2bf(v.y) << 16);
      pk.y = f2bf(v.z) | (f2bf(v.w) << 16);
      *(uint2*)&As[r][q * 4] = pk;
    }
    __syncthreads();
#pragma unroll
    for (int sub = 0; sub < 4; ++sub) {
      short8v a[4];
#pragma unroll
      for (int m = 0; m < 4; ++m)
        a[m] = *(const short8v*)&As[m * 16 + l15][sub * 32 + kA];
      int kk = k0 + sub * 32 + kA;
      const unsigned short* bp = h1t8 + (size_t)(kk >> 3) * 2048;
#pragma unroll
      for (int n = 0; n < 4; ++n) {
        int col = wv * 64 + n * 16 + l15;
        short8v bv = *(const short8v*)(bp + (size_t)col * 8);
#pragma unroll
        for (int m = 0; m < 4; ++m)
          acc[m * 4 + n] = __builtin_amdgcn_mfma_f32_16x16x32_bf16(a[m], bv, acc[m * 4 + n], 0, 0, 0);
      }
    }
    __syncthreads();
  }

  float* tp = tpart + (size_t)blockIdx.x * 16384;
  const int grp = lane >> 4;
#pragma unroll
  for (int m = 0; m < 4; ++m)
#pragma unroll
    for (int n = 0; n < 4; ++n) {
      int col = wv * 64 + n * 16 + l15;
      f32x4 v = acc[m * 4 + n];
#pragma unroll
      for (int r = 0; r < 4; ++r)
        tp[(size_t)(m * 16 + grp * 4 + r) * 256 + col] = v[r];
    }
}

// Non-atomic tree reduce: t2[chunk][g][c] = partial sum over tgemm blocks.
__global__ __launch_bounds__(256)
void k_tred(const float* __restrict__ tpart, float* __restrict__ t2, int NB, int NCH) {
  int g = blockIdx.x & 63;
  int chunk = blockIdx.x >> 6;
  int c = threadIdx.x;
  float s = 0.f;
  for (int b = chunk; b < NB; b += NCH)
    s += tpart[(size_t)b * 16384 + g * 256 + c];
  t2[((size_t)chunk * 64 + g) * 256 + c] = s;
}

// out[g][l] = (sum_ch t2[ch][g]) @ Wc / max(cnt,1) + (cnt>0 ? cb : bl)
__global__ __launch_bounds__(256)
void k_final2(const float* __restrict__ t2, const int* __restrict__ gids,
              const float* __restrict__ Wc, const float* __restrict__ cb,
              const float* __restrict__ bl, float* __restrict__ out,
              int N, int L, int NCH) {
  int g = blockIdx.x;
  __shared__ float ts[256];
  int c = threadIdx.x;
  float s = 0.f;
  for (int ch = 0; ch < NCH; ++ch) s += t2[((size_t)ch * 64 + g) * 256 + c];
  ts[c] = s;
  int lo = 0, hi = N;
  while (lo < hi) { int m = (lo + hi) >> 1; if (gids[m] < g) lo = m + 1; else hi = m; }
  int lo2 = lo, hi2 = N;
  while (lo2 < hi2) { int m = (lo2 + hi2) >> 1; if (gids[m] < g + 1) lo2 = m + 1; else hi2 = m; }
  int cnt = lo2 - lo;
  float inv = 1.0f / (float)(cnt > 1 ? cnt : 1);
  __syncthreads();
  if (c < L) {
    float a = 0.f;
    for (int k = 0; k < 256; ++k) a += ts[k] * Wc[(size_t)k * L + c];
    out[(size_t)g * L + c] = a * inv + (cnt > 0 ? cb[c] : bl[c]);
  }
}

static inline size_t alignup(size_t v) { return (v + 255) & ~(size_t)255; }

extern "C" void kernel_launch(void* const* d_in, const int* in_sizes, int n_in,
                              void* d_out, int out_size, void* d_ws, size_t ws_size,
                              hipStream_t stream) {
  const float* x   = (const float*)d_in[0];
  const int*   src = (const int*)d_in[1];
  const int*   dst = (const int*)d_in[2];
  const int*   gid = (const int*)d_in[3];
  const float* W1  = (const float*)d_in[5];
  const float* b1  = (const float*)d_in[6];
  const float* W2  = (const float*)d_in[7];
  const float* b2  = (const float*)d_in[8];
  const float* Wl  = (const float*)d_in[9];
  const float* bl  = (const float*)d_in[10];
  float* out = (float*)d_out;

  const int N  = in_sizes[3];        // 50000 (even)
  const int E  = in_sizes[1];        // 800000
  const int L  = in_sizes[10];       // 50
  const int G  = out_size / L;       // 64
  const int RB = (N + 127) / 128;    // GEMM1 row blocks
  const int Npad = RB * 128;         // 50048
  const int NB = (Npad + 255) / 256; // tgemm K-chunks (196)
  const int NCH = 16;                // tred part-chunks

  char* p = (char*)d_ws;
  int*   counter    = (int*)p;   p += 256;
  unsigned short* outpart = (unsigned short*)p; p += alignup((size_t)BSLICE * N * 2);
  unsigned short* inpart  = (unsigned short*)p; p += alignup((size_t)BSLICE * N * 2);
  int*   cursor_base= (int*)p;   p += alignup((size_t)BSLICE * N * 4);
  int*   indeg_tot  = (int*)p;   p += alignup((size_t)N * 4);
  float* cj         = (float*)p; p += alignup((size_t)N * 4);
  float* ci         = (float*)p; p += alignup((size_t)N * 4);
  int*   row_start  = (int*)p;   p += alignup((size_t)N * 4);
  int*   csr_src    = (int*)p;   p += alignup((size_t)E * 4);
  unsigned short* xb = (unsigned short*)p; p += alignup((size_t)Npad * 128 * 2);
  unsigned short* a1 = (unsigned short*)p; p += alignup((size_t)Npad * 128 * 2);
  unsigned short* h1t8 = (unsigned short*)p; p += alignup((size_t)Npad * 256 * 2);
  unsigned short* BT1  = (unsigned short*)p; p += alignup((size_t)256 * 128 * 2);
  float* Wg         = (float*)p; p += alignup((size_t)G * Npad * 4);
  float* tpart      = (float*)p; p += alignup((size_t)NB * 64 * 256 * 4);
  float* t2         = (float*)p; p += alignup((size_t)NCH * 64 * 256 * 4);
  float* Wc         = (float*)p; p += alignup((size_t)256 * L * 4);
  float* cb         = (float*)p; p += alignup((size_t)L * 4);
  (void)ws_size; (void)n_in;

  const int SETUP_BLOCKS = 2 * BSLICE * HSPLIT + 128 + 257;   // 513
  k_setup<<<SETUP_BLOCKS, 256, 0, stream>>>(src, dst, W1, W2, Wl, b2, bl,
                                            outpart, inpart, BT1, Wc, cb,
                                            counter, E, N, L);

  k_norms<<<(N + 255) / 256, 256, 0, stream>>>(outpart, inpart, cj, ci, indeg_tot,
                                               row_start, cursor_base, counter, N);

  const int FC_BLOCKS = RSPLIT * BSLICE + (N * 32 + 255) / 256;
  k_fillcast<<<FC_BLOCKS, 256, 0, stream>>>(src, dst, cursor_base, csr_src,
                                            (const float4*)x, cj, xb, E, N);

  k_spmm<<<(N + 3) / 4, 256, 0, stream>>>((const unsigned*)xb, row_start, indeg_tot,
                                          csr_src, (unsigned*)a1, N);

  k_gw<<<RB + RSPLIT * G, 256, 0, stream>>>(a1, BT1, ci, b1, cj, h1t8, N,
                                            gid, row_start, indeg_tot, csr_src,
                                            Wg, Npad, G, RB);

  k_tgemm<<<NB, 256, 0, stream>>>(Wg, h1t8, tpart, Npad);

  k_tred<<<NCH * 64, 256, 0, stream>>>(tpart, t2, NB, NCH);

  k_final2<<<G, 256, 0, stream>>>(t2, gid, Wc, cb, bl, out, N, L, NCH);
}

// Round 17
// 191.959 us; speedup vs baseline: 1.1855x; 1.1855x over previous
//
#include <hip/hip_runtime.h>
#include <cstdint>

// ---------------------------------------------------------------------------
// GCN graph classification on MI355X (gfx950), v17 == v15 (measured 192us).
//   v16's BSLICE=32 reverted: fill needs >=256 blocks (one per CU) more than
//   it needs reduced partial traffic (v16: fill 60us, total 227).
//   k_setup: packed hist(src/dst, HSPLIT=2) + castT + prep + counter zero
//   k_norms: partial sums -> cj,ci,indeg; slice prefix -> CSR cursors
//   k_fillcast: CSR fill (LDS cursors, 256 blocks) ++ xb = bf16(cj*x)
//   a1[n] = sum_{e: dst=n} xb[src]                (unroll-8, predicated tail)
//   k_gw:  h1t8 = bf16(cj*relu((a1@W1)*ci+b1))  ||  Wg[g][s] build
//   tpart = Wg @ h1 (MFMA) ; tred ; final
// ---------------------------------------------------------------------------

typedef __attribute__((ext_vector_type(8))) short short8v;
typedef __attribute__((ext_vector_type(4))) float f32x4;

constexpr int RSPLIT = 4;    // node ranges for fill/wgn (50KB int/f32 LDS)
constexpr int HSPLIT = 2;    // node ranges for packed hist (50KB u32 LDS)
constexpr int BSLICE = 64;   // edge slices
constexpr int LDSN = 12544;  // >= ceil(50048/4) ints/floats
constexpr int LDSH = 12544;  // packed u32 counters (covers 25088 nodes)

static __device__ __forceinline__ unsigned f2bf(float f) {
  unsigned u = __float_as_uint(f);
  u += 0x7FFFu + ((u >> 16) & 1u);   // RTNE
  return u >> 16;
}
static __device__ __forceinline__ float bf2f(unsigned h) {
  return __uint_as_float(h << 16);
}

// Fused setup: blocks [0,256) hist (h in {src,dst} x 64 slices x 2 ranges,
// packed dual-ushort counters in u32 LDS); [256,384) castT(W1->BT1);
// [384,641) prep. Block 0 thread 0 zeroes the scan counter.
__global__ __launch_bounds__(256)
void k_setup(const int* __restrict__ src, const int* __restrict__ dst,
             const float* __restrict__ W1, const float* __restrict__ W2,
             const float* __restrict__ Wl, const float* __restrict__ b2,
             const float* __restrict__ bl,
             unsigned short* __restrict__ outpart, unsigned short* __restrict__ inpart,
             unsigned short* __restrict__ BT1, float* __restrict__ Wc,
             float* __restrict__ cb, int* __restrict__ counter,
             int E, int N, int L) {
  __shared__ unsigned cnt_s[LDSH];
  __shared__ float w2row[256];
  const int blk = blockIdx.x;
  const int tid = threadIdx.x;
  if (blk == 0 && tid == 0) *counter = 0;

  const int NHIST = 2 * BSLICE * HSPLIT;      // 256
  if (blk < NHIST) {                          // packed histogram
    const int h = blk >> 7;                   // 0: src, 1: dst
    const int sub = blk & 127;
    const int b = sub >> 1, r = sub & 1;
    const int* idx = h ? dst : src;
    unsigned short* part = h ? inpart : outpart;
    const int RN = (N + HSPLIT - 1) / HSPLIT; // 25000 (even)
    const int r0 = r * RN;
    int rlen = N - r0; if (rlen > RN) rlen = RN; if (rlen < 0) rlen = 0;
    const int words = (rlen + 1) >> 1;
    for (int i = tid; i < words; i += 256) cnt_s[i] = 0;
    __syncthreads();
    const int e0 = (int)((long long)E * b / BSLICE);
    const int e1 = (int)((long long)E * (b + 1) / BSLICE);
    for (int e = e0 + tid; e < e1; e += 256) {
      int v = idx[e] - r0;
      if (v >= 0 && v < rlen)
        atomicAdd(&cnt_s[v >> 1], 1u << ((v & 1) * 16));
    }
    __syncthreads();
    // part + b*N + r0 is 4B-aligned (N, r0 even); u32 = two ushort counts.
    unsigned* dp = (unsigned*)(part + (size_t)b * N + r0);
    for (int i = tid; i < words; i += 256) dp[i] = cnt_s[i];
  } else if (blk < NHIST + 128) {             // castT: W1[128][256] -> BT1
    int i = (blk - NHIST) * 256 + tid;        // 32768 elems
    int k = i >> 8, nn = i & 255;
    BT1[(size_t)nn * 128 + k] = (unsigned short)f2bf(W1[i]);
  } else {                                    // prep
    int c = blk - (NHIST + 128);              // 0..256
    if (c < 256) {
      w2row[tid] = W2[(size_t)c * 256 + tid]; // coalesced stage
      __syncthreads();
      int l = tid;
      if (l < L) {
        float a = 0.f;
#pragma unroll 8
        for (int m = 0; m < 256; ++m) a += w2row[m] * Wl[(size_t)m * L + l];
        Wc[(size_t)c * L + l] = a;
      }
    } else {
      int l = tid;
      if (l < L) {
        float a = bl[l];
#pragma unroll 8
        for (int m = 0; m < 256; ++m) a += b2[m] * Wl[(size_t)m * L + l];
        cb[l] = a;
      }
    }
  }
}

// Sum partials -> cj/ci/indeg_tot; wave-scan + bump -> row_start; prefix over
// slices -> cursor_base[b][n] (exact CSR write cursors for fill).
__global__ void k_norms(const unsigned short* __restrict__ outpart,
                        const unsigned short* __restrict__ inpart,
                        float* __restrict__ cj, float* __restrict__ ci,
                        int* __restrict__ indeg_tot, int* __restrict__ row_start,
                        int* __restrict__ cursor_base, int* __restrict__ counter, int N) {
  int i = blockIdx.x * blockDim.x + threadIdx.x;
  int din = 0, dout = 0;
  if (i < N) {
    for (int b = 0; b < BSLICE; ++b) {
      din += inpart[(size_t)b * N + i];
      dout += outpart[(size_t)b * N + i];
    }
    cj[i] = rsqrtf((float)(dout > 1 ? dout : 1));
    ci[i] = rsqrtf((float)(din  > 1 ? din  : 1));
    indeg_tot[i] = din;
  }
  int lane = threadIdx.x & 63;
  int inc = din;
#pragma unroll
  for (int off = 1; off < 64; off <<= 1) {
    int o = __shfl_up(inc, off);
    if (lane >= off) inc += o;
  }
  int excl = inc - din;
  int wsum = __shfl(inc, 63);
  int base = 0;
  if (lane == 0) base = atomicAdd(counter, wsum);
  base = __shfl(base, 0);
  if (i < N) {
    int rs = base + excl;
    row_start[i] = rs;
    for (int b = 0; b < BSLICE; ++b) {
      cursor_base[(size_t)b * N + i] = rs;
      rs += inpart[(size_t)b * N + i];
    }
  }
}

// Fused: blocks [0,256) CSR fill (slice b, range r); rest = bf16(cj*x) cast.
__global__ __launch_bounds__(256)
void k_fillcast(const int* __restrict__ src, const int* __restrict__ dst,
                const int* __restrict__ cursor_base, int* __restrict__ csr_src,
                const float4* __restrict__ x, const float* __restrict__ cj,
                unsigned short* __restrict__ xb, int E, int N) {
  __shared__ int cur_s[LDSN];
  const int blk = blockIdx.x;
  if (blk < RSPLIT * BSLICE) {
    const int b = blk >> 2, r = blk & 3;
    const int RN = (N + RSPLIT - 1) / RSPLIT;
    const int r0 = r * RN;
    int rlen = N - r0; if (rlen > RN) rlen = RN; if (rlen < 0) rlen = 0;
    const int* cb_ = cursor_base + (size_t)b * N + r0;
    for (int i = threadIdx.x; i < rlen; i += 256) cur_s[i] = cb_[i];
    __syncthreads();
    const int e0 = (int)((long long)E * b / BSLICE);
    const int e1 = (int)((long long)E * (b + 1) / BSLICE);
    for (int e = e0 + (int)threadIdx.x; e < e1; e += 256) {
      int d = dst[e] - r0;
      if (d >= 0 && d < rlen) {
        int pos = atomicAdd(&cur_s[d], 1);
        csr_src[pos] = src[e];
      }
    }
  } else {
    int i = (blk - RSPLIT * BSLICE) * 256 + (int)threadIdx.x;
    if (i < N * 32) {
      float c = cj[i >> 5];            // 32 float4 per 128-wide row
      float4 v = x[i];
      uint2 r;
      r.x = f2bf(c * v.x) | (f2bf(c * v.y) << 16);
      r.y = f2bf(c * v.z) | (f2bf(c * v.w) << 16);
      *(uint2*)(xb + (size_t)i * 4) = r;
    }
  }
}

// Row-sum gather: wave per node, lane owns 1 uint (2 cols); unroll-8 with
// clamped+masked final batch (no serial tail).
__global__ __launch_bounds__(256)
void k_spmm(const unsigned* __restrict__ feat,
            const int* __restrict__ row_start, const int* __restrict__ cnts,
            const int* __restrict__ csr_src, unsigned* __restrict__ out, int N) {
  const int n = blockIdx.x * 4 + (threadIdx.x >> 6);
  if (n >= N) return;
  const int t = threadIdx.x & 63;
  const int beg = __builtin_amdgcn_readfirstlane(row_start[n]);
  const int cnt = __builtin_amdgcn_readfirstlane(cnts[n]);
  float acc0 = 0.f, acc1 = 0.f;

  for (int k = 0; k < cnt; k += 8) {
    int s[8];
#pragma unroll
    for (int u = 0; u < 8; ++u) {
      int kk = k + u;
      s[u] = csr_src[beg + (kk < cnt ? kk : cnt - 1)];
    }
    unsigned w[8];
#pragma unroll
    for (int u = 0; u < 8; ++u) w[u] = feat[(size_t)s[u] * 64 + t];
#pragma unroll
    for (int u = 0; u < 8; ++u) {
      if (k + u >= cnt) w[u] = 0;      // masked: bf16 +0.0
      acc0 += bf2f(w[u] & 0xFFFF);
      acc1 += bf2f(w[u] >> 16);
    }
  }
  out[(size_t)n * 64 + t] = f2bf(acc0) | (f2bf(acc1) << 16);
}

// Fused GEMM1 || Wg-build. Blocks [0,RB): h1t8 = f(a1@W1) (MFMA, 64KB LDS);
// blocks [RB, RB+RSPLIT*G): Wg row slices (50KB of the same LDS).
__global__ __launch_bounds__(256, 2)
void k_gw(const unsigned short* __restrict__ A, const unsigned short* __restrict__ BT,
          const float* __restrict__ ci, const float* __restrict__ bias,
          const float* __restrict__ cjv, unsigned short* __restrict__ out, int M,
          const int* __restrict__ gids, const int* __restrict__ row_start,
          const int* __restrict__ cnts, const int* __restrict__ csr_src,
          float* __restrict__ Wg, int Npad, int G, int RB) {
  __shared__ unsigned short Bs[64 * 64 * 8];   // 64KB (gemm); reused by wgn
  const int tid = threadIdx.x;

  if ((int)blockIdx.x < RB) {
    // ---------------- GEMM1 ----------------
    constexpr int K = 128;
    const int lane = tid & 63;
    const int wave = tid >> 6;
    const int l15 = lane & 15;
    const int kA = (lane >> 4) * 8;

#pragma unroll
    for (int it = 0; it < 16; ++it) {
      int c = it * 256 + tid;
      int f = c >> 6, l = c & 63;
      int ct = f & 15, kb = f >> 4;
      int col = ct * 16 + (l & 15);
      int ko = kb * 32 + (l >> 4) * 8;
      *(uint4*)&Bs[(size_t)c * 8] = *(const uint4*)(BT + (size_t)col * K + ko);
    }
    __syncthreads();

    const int rowW = blockIdx.x * 128 + wave * 32;
    const unsigned short* aP0 = A + (size_t)(rowW + l15) * K + kA;
    const unsigned short* aP1 = aP0 + (size_t)16 * K;

    short8v a0[4], a1v[4];
#pragma unroll
    for (int kb = 0; kb < 4; ++kb) {
      a0[kb] = *(const short8v*)(aP0 + kb * 32);
      a1v[kb] = *(const short8v*)(aP1 + kb * 32);
    }

    f32x4 acc0[16], acc1[16];
#pragma unroll
    for (int i = 0; i < 16; ++i) {
      acc0[i] = (f32x4){0.f, 0.f, 0.f, 0.f};
      acc1[i] = (f32x4){0.f, 0.f, 0.f, 0.f};
    }

    const unsigned short* bL = Bs + lane * 8;
#pragma unroll
    for (int kb = 0; kb < 4; ++kb) {
#pragma unroll
      for (int ct = 0; ct < 16; ++ct) {
        short8v bv = *(const short8v*)(bL + (size_t)(kb * 16 + ct) * 512);
        acc0[ct] = __builtin_amdgcn_mfma_f32_16x16x32_bf16(a0[kb], bv, acc0[ct], 0, 0, 0);
        acc1[ct] = __builtin_amdgcn_mfma_f32_16x16x32_bf16(a1v[kb], bv, acc1[ct], 0, 0, 0);
      }
    }

#pragma unroll
    for (int half = 0; half < 2; ++half) {
      const f32x4* acc = half ? acc1 : acc0;
      const int row0 = rowW + (lane >> 4) * 4 + half * 16;   // multiple of 4
      float cir[4], cjr[4];
#pragma unroll
      for (int r = 0; r < 4; ++r) {
        int rI = row0 + r; if (rI > M - 1) rI = M - 1;
        cir[r] = ci[rI];
        cjr[r] = cjv[rI];
      }
      unsigned short* ob = out + (size_t)(row0 >> 3) * 2048 + (row0 & 7);
#pragma unroll
      for (int ct = 0; ct < 16; ++ct) {
        int col = ct * 16 + l15;
        float bb = bias[col];
        unsigned h0 = f2bf(fmaxf(acc[ct][0] * cir[0] + bb, 0.f) * cjr[0]);
        unsigned h1 = f2bf(fmaxf(acc[ct][1] * cir[1] + bb, 0.f) * cjr[1]);
        unsigned h2 = f2bf(fmaxf(acc[ct][2] * cir[2] + bb, 0.f) * cjr[2]);
        unsigned h3 = f2bf(fmaxf(acc[ct][3] * cir[3] + bb, 0.f) * cjr[3]);
        uint2 pk;
        pk.x = h0 | (h1 << 16);
        pk.y = h2 | (h3 << 16);
        *(uint2*)(ob + (size_t)col * 8) = pk;
      }
    }
  } else {
    // ---------------- Wg build (LDS-owned row slices) ----------------
    float* row_s = (float*)Bs;                 // 50KB of the 64KB
    const int bid = (int)blockIdx.x - RB;
    const int g = bid % G;
    const int r = bid / G;
    const int RNW = (Npad + RSPLIT - 1) / RSPLIT;
    const int r0 = r * RNW;
    int rlen = Npad - r0; if (rlen > RNW) rlen = RNW; if (rlen < 0) rlen = 0;
    for (int i = tid; i < rlen; i += 256) row_s[i] = 0.f;
    __syncthreads();
    int N_ = M;                                // node count
    int lo = 0, hi = N_;
    while (lo < hi) { int m = (lo + hi) >> 1; if (gids[m] < g) lo = m + 1; else hi = m; }
    int lo2 = lo, hi2 = N_;
    while (lo2 < hi2) { int m = (lo2 + hi2) >> 1; if (gids[m] < g + 1) lo2 = m + 1; else hi2 = m; }
    for (int n = lo + tid; n < lo2; n += 256) {
      float cin = ci[n];
      int beg = row_start[n];
      int cnt = cnts[n];
      for (int k = 0; k < cnt; ++k) {
        int s = csr_src[beg + k] - r0;
        if (s >= 0 && s < rlen) atomicAdd(&row_s[s], cin);
      }
    }
    __syncthreads();
    float* wr = Wg + (size_t)g * Npad + r0;
    for (int i = tid; i < rlen; i += 256) wr[i] = row_s[i];
  }
}

// tpart[blk] = bf16(Wg[:, kchunk]) @ h1[kchunk, :]; K-chunk 256 per block.
__global__ __launch_bounds__(256)
void k_tgemm(const float* __restrict__ Wg, const unsigned short* __restrict__ h1t8,
             float* __restrict__ tpart, int Npad) {
  __shared__ unsigned short As[64][136];
  const int tid = threadIdx.x;
  const int lane = tid & 63;
  const int wv = tid >> 6;
  const int l15 = lane & 15;
  const int kA = (lane >> 4) * 8;

  f32x4 acc[16];
#pragma unroll
  for (int i = 0; i < 16; ++i) acc[i] = (f32x4){0.f, 0.f, 0.f, 0.f};

  const int kbeg = blockIdx.x * 256;
#pragma unroll
  for (int step = 0; step < 2; ++step) {
    int k0 = kbeg + step * 128;
    if (k0 >= Npad) break;
#pragma unroll
    for (int it = 0; it < 8; ++it) {
      int idx = it * 256 + tid;
      int r = idx >> 5, q = idx & 31;
      float4 v = *(const float4*)(Wg + (size_t)r * Npad + k0 + q * 4);
      uint2 pk;
      pk.x = f2bf(v.x) | (f2bf(v.y) << 16);
      pk.y = f2bf(v.z) | (f2bf(v.w) << 16);
      *(uint2*)&As[r][q * 4] = pk;
    }
    __syncthreads();
#pragma unroll
    for (int sub = 0; sub < 4; ++sub) {
      short8v a[4];
#pragma unroll
      for (int m = 0; m < 4; ++m)
        a[m] = *(const short8v*)&As[m * 16 + l15][sub * 32 + kA];
      int kk = k0 + sub * 32 + kA;
      const unsigned short* bp = h1t8 + (size_t)(kk >> 3) * 2048;
#pragma unroll
      for (int n = 0; n < 4; ++n) {
        int col = wv * 64 + n * 16 + l15;
        short8v bv = *(const short8v*)(bp + (size_t)col * 8);
#pragma unroll
        for (int m = 0; m < 4; ++m)
          acc[m * 4 + n] = __builtin_amdgcn_mfma_f32_16x16x32_bf16(a[m], bv, acc[m * 4 + n], 0, 0, 0);
      }
    }
    __syncthreads();
  }

  float* tp = tpart + (size_t)blockIdx.x * 16384;
  const int grp = lane >> 4;
#pragma unroll
  for (int m = 0; m < 4; ++m)
#pragma unroll
    for (int n = 0; n < 4; ++n) {
      int col = wv * 64 + n * 16 + l15;
      f32x4 v = acc[m * 4 + n];
#pragma unroll
      for (int r = 0; r < 4; ++r)
        tp[(size_t)(m * 16 + grp * 4 + r) * 256 + col] = v[r];
    }
}

// Non-atomic tree reduce: t2[chunk][g][c] = partial sum over tgemm blocks.
__global__ __launch_bounds__(256)
void k_tred(const float* __restrict__ tpart, float* __restrict__ t2, int NB, int NCH) {
  int g = blockIdx.x & 63;
  int chunk = blockIdx.x >> 6;
  int c = threadIdx.x;
  float s = 0.f;
  for (int b = chunk; b < NB; b += NCH)
    s += tpart[(size_t)b * 16384 + g * 256 + c];
  t2[((size_t)chunk * 64 + g) * 256 + c] = s;
}

// out[g][l] = (sum_ch t2[ch][g]) @ Wc / max(cnt,1) + (cnt>0 ? cb : bl)
__global__ __launch_bounds__(256)
void k_final2(const float* __restrict__ t2, const int* __restrict__ gids,
              const float* __restrict__ Wc, const float* __restrict__ cb,
              const float* __restrict__ bl, float* __restrict__ out,
              int N, int L, int NCH) {
  int g = blockIdx.x;
  __shared__ float ts[256];
  int c = threadIdx.x;
  float s = 0.f;
  for (int ch = 0; ch < NCH; ++ch) s += t2[((size_t)ch * 64 + g) * 256 + c];
  ts[c] = s;
  int lo = 0, hi = N;
  while (lo < hi) { int m = (lo + hi) >> 1; if (gids[m] < g) lo = m + 1; else hi = m; }
  int lo2 = lo, hi2 = N;
  while (lo2 < hi2) { int m = (lo2 + hi2) >> 1; if (gids[m] < g + 1) lo2 = m + 1; else hi2 = m; }
  int cnt = lo2 - lo;
  float inv = 1.0f / (float)(cnt > 1 ? cnt : 1);
  __syncthreads();
  if (c < L) {
    float a = 0.f;
    for (int k = 0; k < 256; ++k) a += ts[k] * Wc[(size_t)k * L + c];
    out[(size_t)g * L + c] = a * inv + (cnt > 0 ? cb[c] : bl[c]);
  }
}

static inline size_t alignup(size_t v) { return (v + 255) & ~(size_t)255; }

extern "C" void kernel_launch(void* const* d_in, const int* in_sizes, int n_in,
                              void* d_out, int out_size, void* d_ws, size_t ws_size,
                              hipStream_t stream) {
  const float* x   = (const float*)d_in[0];
  const int*   src = (const int*)d_in[1];
  const int*   dst = (const int*)d_in[2];
  const int*   gid = (const int*)d_in[3];
  const float* W1  = (const float*)d_in[5];
  const float* b1  = (const float*)d_in[6];
  const float* W2  = (const float*)d_in[7];
  const float* b2  = (const float*)d_in[8];
  const float* Wl  = (const float*)d_in[9];
  const float* bl  = (const float*)d_in[10];
  float* out = (float*)d_out;

  const int N  = in_sizes[3];        // 50000 (even)
  const int E  = in_sizes[1];        // 800000
  const int L  = in_sizes[10];       // 50
  const int G  = out_size / L;       // 64
  const int RB = (N + 127) / 128;    // GEMM1 row blocks
  const int Npad = RB * 128;         // 50048
  const int NB = (Npad + 255) / 256; // tgemm K-chunks (196)
  const int NCH = 16;                // tred part-chunks

  char* p = (char*)d_ws;
  int*   counter    = (int*)p;   p += 256;
  unsigned short* outpart = (unsigned short*)p; p += alignup((size_t)BSLICE * N * 2);
  unsigned short* inpart  = (unsigned short*)p; p += alignup((size_t)BSLICE * N * 2);
  int*   cursor_base= (int*)p;   p += alignup((size_t)BSLICE * N * 4);
  int*   indeg_tot  = (int*)p;   p += alignup((size_t)N * 4);
  float* cj         = (float*)p; p += alignup((size_t)N * 4);
  float* ci         = (float*)p; p += alignup((size_t)N * 4);
  int*   row_start  = (int*)p;   p += alignup((size_t)N * 4);
  int*   csr_src    = (int*)p;   p += alignup((size_t)E * 4);
  unsigned short* xb = (unsigned short*)p; p += alignup((size_t)Npad * 128 * 2);
  unsigned short* a1 = (unsigned short*)p; p += alignup((size_t)Npad * 128 * 2);
  unsigned short* h1t8 = (unsigned short*)p; p += alignup((size_t)Npad * 256 * 2);
  unsigned short* BT1  = (unsigned short*)p; p += alignup((size_t)256 * 128 * 2);
  float* Wg         = (float*)p; p += alignup((size_t)G * Npad * 4);
  float* tpart      = (float*)p; p += alignup((size_t)NB * 64 * 256 * 4);
  float* t2         = (float*)p; p += alignup((size_t)NCH * 64 * 256 * 4);
  float* Wc         = (float*)p; p += alignup((size_t)256 * L * 4);
  float* cb         = (float*)p; p += alignup((size_t)L * 4);
  (void)ws_size; (void)n_in;

  const int SETUP_BLOCKS = 2 * BSLICE * HSPLIT + 128 + 257;   // 641
  k_setup<<<SETUP_BLOCKS, 256, 0, stream>>>(src, dst, W1, W2, Wl, b2, bl,
                                            outpart, inpart, BT1, Wc, cb,
                                            counter, E, N, L);

  k_norms<<<(N + 255) / 256, 256, 0, stream>>>(outpart, inpart, cj, ci, indeg_tot,
                                               row_start, cursor_base, counter, N);

  const int FC_BLOCKS = RSPLIT * BSLICE + (N * 32 + 255) / 256;
  k_fillcast<<<FC_BLOCKS, 256, 0, stream>>>(src, dst, cursor_base, csr_src,
                                            (const float4*)x, cj, xb, E, N);

  k_spmm<<<(N + 3) / 4, 256, 0, stream>>>((const unsigned*)xb, row_start, indeg_tot,
                                          csr_src, (unsigned*)a1, N);

  k_gw<<<RB + RSPLIT * G, 256, 0, stream>>>(a1, BT1, ci, b1, cj, h1t8, N,
                                            gid, row_start, indeg_tot, csr_src,
                                            Wg, Npad, G, RB);

  k_tgemm<<<NB, 256, 0, stream>>>(Wg, h1t8, tpart, Npad);

  k_tred<<<NCH * 64, 256, 0, stream>>>(tpart, t2, NB, NCH);

  k_final2<<<G, 256, 0, stream>>>(t2, gid, Wc, cb, bl, out, N, L, NCH);
}